// Round 14
// baseline (22.141 us; speedup 1.0000x reference)
//
#include <hip/hip_runtime.h>

#define N 64
#define LC 64
#define LD 32
#define NPAIRS 1953             // #(i,k): 0<=i<=k<=61  (62*63/2)
#define CONT_BLOCKS 4           // 4 blocks * 4 waves * 256 cells = 4096
#define PAIR_BLOCKS 489         // ceil(1953/4), one pair per wave

typedef __attribute__((ext_vector_type(8))) short short8;   // 8 bf16 (4 VGPR)
typedef __attribute__((ext_vector_type(4))) float f32x4;

// float -> bf16 bits, round-to-nearest-even
__device__ inline unsigned f2bf(float f) {
    unsigned u = __float_as_uint(f);
    u += 0x7FFF + ((u >> 16) & 1);
    return u >> 16;
}
__device__ inline float bf2f(unsigned u) {
    return __uint_as_float(u << 16);
}

__global__ __launch_bounds__(256, 4) void loss_kernel(
    const float* __restrict__ cont_w,   // [N,N,LC]
    const float* __restrict__ disc_w,   // [N,N,LD]  ("dw")
    const float* __restrict__ gap_w,    // [N,N,LD]  ("gw")
    const int*   __restrict__ cont_gold,// [N,N] values 0..LC
    const int*   __restrict__ disc_gold,// [T]   values 0..LD
    float* __restrict__ partials)
{
    // Per-WAVE private tables; no __syncthreads in this kernel at all.
    __shared__ unsigned short EgB[4][64 * 32];   // exp(gw slab), A operand (l)
    __shared__ unsigned short EdB[4][64 * 32];   // exp(dw slab), B operand (j)

    const int wid  = threadIdx.x >> 6;           // wave in block, 0..3
    const int lane = threadIdx.x & 63;

    float acc = 0.0f;

    if (blockIdx.x < CONT_BLOCKS) {
        // ---- continuous part: one 256-cell unit per wave, 4 cells/lane ----
        const int u = blockIdx.x * 4 + wid;      // 0..15
        #pragma unroll
        for (int it = 0; it < 4; ++it) {
            const int idx = u * 256 + it * 64 + lane;     // 0..4095
            const int ii = idx >> 6, jj = idx & 63;
            if (ii <= jj) {
                const float4* p =
                    reinterpret_cast<const float4*>(cont_w + idx * LC);
                const int g = cont_gold[idx];    // 0..LC (LC == null col)
                const float goldv = (g < LC) ? cont_w[idx * LC + g] : 0.0f;
                float s0 = 1.0f, s1 = 0.0f, s2 = 0.0f, s3 = 0.0f;
                #pragma unroll
                for (int q = 0; q < LC / 4; ++q) {
                    float4 x = p[q];
                    s0 += __expf(x.x); s1 += __expf(x.y);
                    s2 += __expf(x.z); s3 += __expf(x.w);
                }
                acc += __logf((s0 + s1) + (s2 + s3)) - goldv;
            }
        }
    } else {
        // ---- discontinuous part: ONE (i,k) pair per wave ----
        const int w = (blockIdx.x - CONT_BLOCKS) * 4 + wid;
        if (w < NPAIRS) {
            int k = (int)((sqrtf(8.0f * (float)w + 1.0f) - 1.0f) * 0.5f);
            while (k * (k + 1) / 2 > w) --k;
            while ((k + 1) * (k + 2) / 2 <= w) ++k;
            const int i = w - k * (k + 1) / 2;   // 0..k
            const int M = 62 - k;                // #rows in both slabs
            const int MT   = (M + 15) >> 4;
            const int MT16 = MT << 4;

            // ---- stage (wave-local; LDS r/w same wave => no barrier) ----
            const float4* srcD = reinterpret_cast<const float4*>(
                disc_w + ((i << 6) + (k + 2)) * LD);
            const float4* srcG = reinterpret_cast<const float4*>(
                gap_w + (((k + 1) << 6) + (k + 1)) * LD);
            for (int e = lane; e < MT16 * 8; e += 64) {
                const int r = e >> 3, ch = e & 7;
                uint2* pd = reinterpret_cast<uint2*>(&EdB[wid][r * 32 + ch * 4]);
                uint2* pg = reinterpret_cast<uint2*>(&EgB[wid][r * 32 + ch * 4]);
                if (r < M) {
                    float4 x = srcD[e];
                    float4 y = srcG[e];
                    uint2 xd = { (f2bf(__expf(x.y)) << 16) | f2bf(__expf(x.x)),
                                 (f2bf(__expf(x.w)) << 16) | f2bf(__expf(x.z)) };
                    uint2 yg = { (f2bf(__expf(y.y)) << 16) | f2bf(__expf(y.x)),
                                 (f2bf(__expf(y.w)) << 16) | f2bf(__expf(y.z)) };
                    *pd = xd;
                    *pg = yg;
                } else {
                    uint2 z = {0u, 0u};
                    *pd = z;
                    *pg = z;
                }
            }

            // ---- MFMA: S[l][j] = sum_k Eg[l][k]*Ed[j][k], upper-tri ----
            const int ntiles = MT * (MT + 1) / 2;
            const int r16 = lane & 15;
            const int g4  = lane >> 4;
            for (int p = 0; p < ntiles; ++p) {
                int tr = 0, base = 0;
                while (base + (MT - tr) <= p) { base += MT - tr; ++tr; }
                const int tc = tr + (p - base);
                short8 a = *reinterpret_cast<const short8*>(
                    &EgB[wid][(tr * 16 + r16) * 32 + g4 * 8]);
                short8 b = *reinterpret_cast<const short8*>(
                    &EdB[wid][(tc * 16 + r16) * 32 + g4 * 8]);
                f32x4 c = {0.0f, 0.0f, 0.0f, 0.0f};
                c = __builtin_amdgcn_mfma_f32_16x16x32_bf16(a, b, c, 0, 0, 0);
                #pragma unroll
                for (int q = 0; q < 4; ++q) {
                    const int l = tr * 16 + g4 * 4 + q;   // D row
                    const int j = tc * 16 + r16;          // D col
                    if (j < M && l <= j)
                        acc += __logf(c[q] + 1.0f);       // +1 = null column
                }
            }

            // ---- gold pass: per-lane contiguous chunk, incremental walk ----
            const int A  = 62 - i;
            const int fA = A * (A + 1) * (A + 2) * (A + 3) / 24;
            const int hA = A * (A + 1) * (A + 2) / 6;
            const int hK = M * (M + 1) * (M + 2) / 6;
            const int t0 = (677040 - fA) + (hA - hK);
            const int cells = M * (M + 1) / 2;

            const int Bc = (cells + 63) >> 6;
            const int c0 = lane * Bc;
            const int c1 = min(c0 + Bc, cells);
            if (c0 < c1) {
                const float twoM1 = (float)(2 * M + 1);
                int l = (int)((twoM1 -
                    sqrtf(twoM1 * twoM1 - 8.0f * (float)c0)) * 0.5f);
                if (l < 0) l = 0;
                if (l > M - 1) l = M - 1;
                while (l * M - l * (l - 1) / 2 > c0) --l;
                while ((l + 1) * M - (l + 1) * l / 2 <= c0) ++l;
                int j = l + (c0 - (l * M - l * (l - 1) / 2));
                for (int c = c0; c < c1; ++c) {
                    const int g = disc_gold[t0 + c];
                    if (g < LD) {
                        const float ed = bf2f(EdB[wid][j * 32 + g]);
                        const float eg = bf2f(EgB[wid][l * 32 + g]);
                        acc -= __logf(ed * eg);
                    }
                    ++j;
                    if (j >= M) { ++l; j = l; }
                }
            }
        }
    }

    // ---- per-wave reduction; every wave writes its partial ----
    #pragma unroll
    for (int off = 32; off > 0; off >>= 1)
        acc += __shfl_down(acc, off, 64);
    if (lane == 0)
        partials[blockIdx.x * 4 + wid] = acc;
}

__global__ __launch_bounds__(1024) void reduce_kernel(
    const float* __restrict__ partials, float* __restrict__ out, int nparts)
{
    float acc = 0.0f;
    for (int i = threadIdx.x; i < nparts; i += 1024)
        acc += partials[i];
    #pragma unroll
    for (int off = 32; off > 0; off >>= 1)
        acc += __shfl_down(acc, off, 64);

    __shared__ float ws[16];
    const int lane = threadIdx.x & 63;
    const int wid  = threadIdx.x >> 6;
    if (lane == 0) ws[wid] = acc;
    __syncthreads();
    if (threadIdx.x == 0) {
        float s = 0.0f;
        #pragma unroll
        for (int w = 0; w < 16; ++w) s += ws[w];
        out[0] = s;
    }
}

extern "C" void kernel_launch(void* const* d_in, const int* in_sizes, int n_in,
                              void* d_out, int out_size, void* d_ws, size_t ws_size,
                              hipStream_t stream) {
    const float* cont_w    = (const float*)d_in[0];
    const float* disc_w    = (const float*)d_in[1];
    const float* gap_w     = (const float*)d_in[2];
    const int*   cont_gold = (const int*)d_in[3];
    const int*   disc_gold = (const int*)d_in[4];
    float* out      = (float*)d_out;
    float* partials = (float*)d_ws;

    const int blocks = CONT_BLOCKS + PAIR_BLOCKS;     // 493
    loss_kernel<<<blocks, 256, 0, stream>>>(cont_w, disc_w, gap_w, cont_gold,
                                            disc_gold, partials);
    reduce_kernel<<<1, 1024, 0, stream>>>(partials, out, blocks * 4);
}

// Round 15
// 13.302 us; speedup vs baseline: 1.6645x; 1.6645x over previous
//
#include <hip/hip_runtime.h>

#define N 64
#define LC 64
#define LD 32
#define NCONT (N * N)
#define CONT_BLOCKS 16          // 16 * 256 = 4096 cells
#define NPAIRS 1953             // #(i,k): 0<=i<=k<=61  (62*63/2)
#define RAWPAD 33               // raw-row LDS stride: bank = j+g, conflict-free

typedef __attribute__((ext_vector_type(8))) short short8;   // 8 bf16 (4 VGPR)
typedef __attribute__((ext_vector_type(4))) float f32x4;

// float -> bf16 bits, round-to-nearest-even
__device__ inline unsigned short f2bf(float f) {
    unsigned u = __float_as_uint(f);
    u += 0x7FFF + ((u >> 16) & 1);
    return (unsigned short)(u >> 16);
}

// Block-wide sum over 256 threads (4 waves). Result valid on thread 0.
__device__ inline float block_sum(float v, float* ws) {
    #pragma unroll
    for (int off = 32; off > 0; off >>= 1)
        v += __shfl_down(v, off, 64);
    const int lane = threadIdx.x & 63;
    const int wid  = threadIdx.x >> 6;
    if (lane == 0) ws[wid] = v;
    __syncthreads();
    return ws[0] + ws[1] + ws[2] + ws[3];
}

__global__ __launch_bounds__(256, 4) void loss_kernel(
    const float* __restrict__ cont_w,   // [N,N,LC]
    const float* __restrict__ disc_w,   // [N,N,LD]  ("dw")
    const float* __restrict__ gap_w,    // [N,N,LD]  ("gw")
    const int*   __restrict__ cont_gold,// [N,N] values 0..LC
    const int*   __restrict__ disc_gold,// [T]   values 0..LD
    float* __restrict__ partials, int T)
{
    __shared__ unsigned short EgB[64 * 32];   // bf16 exp(gw slab), A operand (l)
    __shared__ unsigned short EdB[64 * 32];   // bf16 exp(dw slab), B operand (j)
    __shared__ float Draw[62 * RAWPAD];       // raw dw rows (gold)
    __shared__ float Graw[62 * RAWPAD];       // raw gw rows (gold)
    __shared__ float ws[4];

    float acc = 0.0f;

    if (blockIdx.x < CONT_BLOCKS) {
        // ---- continuous part: one cell per thread, upper triangle only ----
        const int idx = blockIdx.x * 256 + threadIdx.x;   // 0..4095
        const int i = idx >> 6, j = idx & 63;
        if (i <= j) {
            const float4* p = reinterpret_cast<const float4*>(cont_w + idx * LC);
            const int g = cont_gold[idx];            // 0..LC (LC == null col)
            const float goldv = (g < LC) ? cont_w[idx * LC + g] : 0.0f;
            float s0 = 1.0f, s1 = 0.0f, s2 = 0.0f, s3 = 0.0f;  // 1.0 = null col
            #pragma unroll
            for (int q = 0; q < LC / 4; ++q) {
                float4 x = p[q];
                s0 += __expf(x.x); s1 += __expf(x.y);
                s2 += __expf(x.z); s3 += __expf(x.w);
            }
            acc = __logf((s0 + s1) + (s2 + s3)) - goldv;
        }
    } else {
        // ---- discontinuous part: one workgroup per (i,k) pair ----
        const int w = blockIdx.x - CONT_BLOCKS;           // 0..1952
        int k = (int)((sqrtf(8.0f * (float)w + 1.0f) - 1.0f) * 0.5f);
        while (k * (k + 1) / 2 > w) --k;
        while ((k + 1) * (k + 2) / 2 <= w) ++k;
        const int i = w - k * (k + 1) / 2;                // 0..k
        const int M = 62 - k;                             // #rows in both slabs

        // ---- stage: exp(bf16) tables (zero-padded to 64 rows) + raw rows ----
        const float4* srcD = reinterpret_cast<const float4*>(
            disc_w + ((i << 6) + (k + 2)) * LD);
        const float4* srcG = reinterpret_cast<const float4*>(
            gap_w + (((k + 1) << 6) + (k + 1)) * LD);
        for (int e = threadIdx.x; e < 64 * 8; e += 256) {
            const int r = e >> 3, ch = e & 7;
            unsigned short* pd = &EdB[r * 32 + ch * 4];
            unsigned short* pg = &EgB[r * 32 + ch * 4];
            if (r < M) {
                float4 x = srcD[e];
                float4 y = srcG[e];
                pd[0] = f2bf(__expf(x.x)); pd[1] = f2bf(__expf(x.y));
                pd[2] = f2bf(__expf(x.z)); pd[3] = f2bf(__expf(x.w));
                pg[0] = f2bf(__expf(y.x)); pg[1] = f2bf(__expf(y.y));
                pg[2] = f2bf(__expf(y.z)); pg[3] = f2bf(__expf(y.w));
                *reinterpret_cast<float4*>(&Draw[r * RAWPAD + ch * 4]) = x;
                *reinterpret_cast<float4*>(&Graw[r * RAWPAD + ch * 4]) = y;
            } else {
                pd[0] = 0; pd[1] = 0; pd[2] = 0; pd[3] = 0;   // bf16 zero
                pg[0] = 0; pg[1] = 0; pg[2] = 0; pg[3] = 0;
            }
        }
        __syncthreads();

        // ---- MFMA: S[l][j] = sum_k Eg[l][k]*Ed[j][k], upper-tri tiles ----
        const int MT = (M + 15) >> 4;                     // tiles per dim
        const int ntiles = MT * (MT + 1) / 2;
        const int wid  = threadIdx.x >> 6;
        const int lane = threadIdx.x & 63;
        const int r16  = lane & 15;
        const int g4   = lane >> 4;
        for (int p = wid; p < ntiles; p += 4) {
            int tr = 0, base = 0;
            while (base + (MT - tr) <= p) { base += MT - tr; ++tr; }
            const int tc = tr + (p - base);
            short8 a = *reinterpret_cast<const short8*>(
                &EgB[(tr * 16 + r16) * 32 + g4 * 8]);
            short8 b = *reinterpret_cast<const short8*>(
                &EdB[(tc * 16 + r16) * 32 + g4 * 8]);
            f32x4 c = {0.0f, 0.0f, 0.0f, 0.0f};
            c = __builtin_amdgcn_mfma_f32_16x16x32_bf16(a, b, c, 0, 0, 0);
            #pragma unroll
            for (int q = 0; q < 4; ++q) {
                const int l = tr * 16 + g4 * 4 + q;       // D row
                const int j = tc * 16 + r16;              // D col
                if (j < M && l <= j)
                    acc += __logf(c[q] + 1.0f);           // +1 = null column
            }
        }

        // ---- gold pass: coalesced disc_gold + conflict-free LDS lookups ----
        const int A  = 62 - i;
        const int fA = A * (A + 1) * (A + 2) * (A + 3) / 24;
        const int hA = A * (A + 1) * (A + 2) / 6;
        const int hK = M * (M + 1) * (M + 2) / 6;
        const int t0 = (677040 - fA) + (hA - hK);
        const int cells = M * (M + 1) / 2;

        const int Bc = (cells + 255) >> 8;
        const int c0 = threadIdx.x * Bc;
        const int c1 = min(c0 + Bc, cells);
        if (c0 < c1) {
            const float twoM1 = (float)(2 * M + 1);
            int l = (int)((twoM1 - sqrtf(twoM1 * twoM1 - 8.0f * (float)c0)) * 0.5f);
            if (l < 0) l = 0; if (l > M - 1) l = M - 1;
            while (l * M - l * (l - 1) / 2 > c0) --l;
            while ((l + 1) * M - (l + 1) * l / 2 <= c0) ++l;
            int j = l + (c0 - (l * M - l * (l - 1) / 2));
            for (int c = c0; c < c1; ++c) {
                const int g = disc_gold[t0 + c];          // coalesced
                if (g < LD)
                    acc -= Draw[j * RAWPAD + g] + Graw[l * RAWPAD + g];
                ++j;
                if (j >= M) { ++l; j = l; }
            }
        }
    }

    const float bsum = block_sum(acc, ws);
    if (threadIdx.x == 0)
        partials[blockIdx.x] = bsum;                      // NO atomics/fences
}

__global__ __launch_bounds__(1024) void reduce_kernel(
    const float* __restrict__ partials, float* __restrict__ out, int nblocks)
{
    float acc = 0.0f;
    for (int i = threadIdx.x; i < nblocks; i += 1024)
        acc += partials[i];
    #pragma unroll
    for (int off = 32; off > 0; off >>= 1)
        acc += __shfl_down(acc, off, 64);

    __shared__ float ws[16];
    const int lane = threadIdx.x & 63;
    const int wid  = threadIdx.x >> 6;
    if (lane == 0) ws[wid] = acc;
    __syncthreads();
    if (threadIdx.x == 0) {
        float s = 0.0f;
        #pragma unroll
        for (int w = 0; w < 16; ++w) s += ws[w];
        out[0] = s;
    }
}

extern "C" void kernel_launch(void* const* d_in, const int* in_sizes, int n_in,
                              void* d_out, int out_size, void* d_ws, size_t ws_size,
                              hipStream_t stream) {
    const float* cont_w    = (const float*)d_in[0];
    const float* disc_w    = (const float*)d_in[1];
    const float* gap_w     = (const float*)d_in[2];
    const int*   cont_gold = (const int*)d_in[3];
    const int*   disc_gold = (const int*)d_in[4];
    float* out      = (float*)d_out;
    float* partials = (float*)d_ws;
    const int T = in_sizes[4];

    const int blocks = CONT_BLOCKS + NPAIRS;          // 1969
    loss_kernel<<<blocks, 256, 0, stream>>>(cont_w, disc_w, gap_w, cont_gold,
                                            disc_gold, partials, T);
    reduce_kernel<<<1, 1024, 0, stream>>>(partials, out, blocks);
}